// Round 4
// baseline (682.948 us; speedup 1.0000x reference)
//
#include <hip/hip_runtime.h>
#include <math.h>

#define DIM 128
#define MSZ 50
#define BB 64
#define NN 200
#define SLEN 25
#define K1SEG 7        // aggregates needed only for segments 0..6

typedef float f4 __attribute__((ext_vector_type(4)));

// LDS pool layout (floats)
#define OFF_K   0       // k tile          [25][128]
#define OFF_S   3200    // s tile (stage1) / rp half h=0 (scan)
#define OFF_RP1 6400    // rp half h=1 (K2 scan only)
#define OFF_W   9600    // w tile          [25][52]
#define OFF_E   10900   // e tile          [25][128]
#define OFF_A   14100   // ad tile         [25][128]
#define OFF_Q   17300   // q/x/ax indices  (3 x 32 ints)
#define OFF_PP  17400   // p partials      [25][16]
#define POOLSZ  17800   // 71.2 KB -> 2 blocks/CU

// ---- stage1: gather + e/ad GEMVs + logits + softmax, all into LDS ----
__device__ __forceinline__ void stage1(
    float* P, int b, int t0, int tid,
    const int* __restrict__ q, const int* __restrict__ r, const int* __restrict__ a,
    const float* __restrict__ Kemb, const float* __restrict__ Vemb,
    const float* __restrict__ VAemb, const float* __restrict__ Mk,
    const float* __restrict__ eW, const float* __restrict__ eb,
    const float* __restrict__ aW, const float* __restrict__ ab)
{
    if (tid < SLEN) {
        int pos = b * NN + t0 + tid;
        int qi = q[pos], ri = r[pos], ai = a[pos];
        ((int*)P)[OFF_Q + tid]      = qi;
        ((int*)P)[OFF_Q + 32 + tid] = qi + 10000 * ri;
        ((int*)P)[OFF_Q + 64 + tid] = ai + 10000 * ri;
    }
    __syncthreads();

    const int* qs = (const int*)P + OFF_Q;
    for (int idx = tid; idx < SLEN * DIM; idx += 256) {
        int pl = idx >> 7, dc = idx & 127;
        P[OFF_K + idx] = Kemb[(size_t)qs[pl] * DIM + dc];
        P[OFF_S + idx] = Vemb[(size_t)qs[32 + pl] * DIM + dc]
                       + VAemb[(size_t)qs[64 + pl] * DIM + dc];
    }
    __syncthreads();

    // e/ad GEMVs: 800 units = 25 pos x {e,ad} x 16 groups of 8 outputs
    const f4* s4 = (const f4*)(P + OFF_S);
    for (int u = tid; u < 800; u += 256) {
        int pos = u >> 5, og = u & 31;
        int half = og >> 4, d0 = (og & 15) * 8;
        const f4* W4 = (const f4*)(half ? aW : eW);
        f4 acc[8];
        #pragma unroll
        for (int j = 0; j < 8; ++j) acc[j] = f4{0.f, 0.f, 0.f, 0.f};
        for (int i4 = 0; i4 < 32; ++i4) {
            f4 sv = s4[pos * 32 + i4];
            #pragma unroll
            for (int j = 0; j < 8; ++j)
                acc[j] += sv * W4[(d0 + j) * 32 + i4];
        }
        #pragma unroll
        for (int j = 0; j < 8; ++j) {
            float v = acc[j].x + acc[j].y + acc[j].z + acc[j].w;
            int d = d0 + j;
            if (half) P[OFF_A + pos * DIM + d] = tanhf(v + ab[d]);
            else      P[OFF_E + pos * DIM + d] = 1.f / (1.f + __expf(-(v + eb[d])));
        }
    }

    // logits: 1250 units of (pos, m)
    const f4* k4  = (const f4*)(P + OFF_K);
    const f4* Mk4 = (const f4*)Mk;
    for (int u = tid; u < SLEN * MSZ; u += 256) {
        int pos = u / MSZ, m = u - pos * MSZ;
        f4 acc = f4{0.f, 0.f, 0.f, 0.f};
        for (int i4 = 0; i4 < 32; ++i4)
            acc += k4[pos * 32 + i4] * Mk4[m * 32 + i4];
        P[OFF_W + pos * 52 + m] = acc.x + acc.y + acc.z + acc.w;
    }
    __syncthreads();

    // softmax over m, one row per thread
    if (tid < SLEN) {
        float mx = -1e30f;
        for (int m = 0; m < MSZ; ++m) mx = fmaxf(mx, P[OFF_W + tid * 52 + m]);
        float sm = 0.f;
        for (int m = 0; m < MSZ; ++m) {
            float ex = __expf(P[OFF_W + tid * 52 + m] - mx);
            P[OFF_W + tid * 52 + m] = ex;
            sm += ex;
        }
        float inv = 1.f / sm;
        for (int m = 0; m < MSZ; ++m) P[OFF_W + tid * 52 + m] *= inv;
    }
    __syncthreads();
}

// ---- K1: stage1 + per-segment affine aggregates (A,B) ----
__global__ __launch_bounds__(256) void dkvmn_k1(
    const int* __restrict__ q, const int* __restrict__ r, const int* __restrict__ a,
    const float* __restrict__ Kemb, const float* __restrict__ Vemb,
    const float* __restrict__ VAemb, const float* __restrict__ Mk,
    const float* __restrict__ eW, const float* __restrict__ eb,
    const float* __restrict__ aW, const float* __restrict__ ab,
    float* __restrict__ Aseg, float* __restrict__ Bseg)
{
    __shared__ float P[POOLSZ];
    const int bid = blockIdx.x;
    const int b = bid / K1SEG, seg = bid - b * K1SEG;
    const int tid = threadIdx.x;

    stage1(P, b, seg * SLEN, tid, q, r, a, Kemb, Vemb, VAemb, Mk, eW, eb, aW, ab);

    const int d = tid & 127, h = tid >> 7;
    float A[SLEN], Bv[SLEN];
    #pragma unroll
    for (int j = 0; j < SLEN; ++j) { A[j] = 1.f; Bv[j] = 0.f; }

    for (int tc = 0; tc < SLEN; ++tc) {
        float ev = P[OFF_E + tc * DIM + d], av = P[OFF_A + tc * DIM + d];
        #pragma unroll
        for (int j = 0; j < SLEN; ++j) {
            float wj = P[OFF_W + tc * 52 + h * SLEN + j];
            float f = fmaf(-wj, ev, 1.f);
            Bv[j] = fmaf(Bv[j], f, wj * av);
            A[j] *= f;
        }
    }
    size_t base = (size_t)bid * (MSZ * DIM) + (size_t)(h * SLEN) * DIM + d;
    #pragma unroll
    for (int j = 0; j < SLEN; ++j) {
        Aseg[base + j * DIM] = A[j];
        Bseg[base + j * DIM] = Bv[j];
    }
}

// ---- K2: prefix-combine + stage1 recompute + scan (Mv stream) + fused f/p ----
__global__ __launch_bounds__(256) void dkvmn_k2(
    const int* __restrict__ q, const int* __restrict__ r, const int* __restrict__ a,
    const float* __restrict__ Kemb, const float* __restrict__ Vemb,
    const float* __restrict__ VAemb, const float* __restrict__ Mk,
    const float* __restrict__ eW, const float* __restrict__ eb,
    const float* __restrict__ aW, const float* __restrict__ ab,
    const float* __restrict__ Mv0,
    const float* __restrict__ Aseg, const float* __restrict__ Bseg,
    const float* __restrict__ fW, const float* __restrict__ fb,
    const float* __restrict__ pW, const float* __restrict__ pb,
    float* __restrict__ p_out, float* __restrict__ Mv)
{
    __shared__ float P[POOLSZ];
    const int bid = blockIdx.x;
    const int b = bid >> 3, seg = bid & 7;
    const int tid = threadIdx.x;
    const int t0 = seg * SLEN;
    const int d = tid & 127, h = tid >> 7;

    // segment-start state via affine prefix combine
    float M[SLEN];
    #pragma unroll
    for (int j = 0; j < SLEN; ++j) M[j] = Mv0[(h * SLEN + j) * DIM + d];
    for (int s = 0; s < seg; ++s) {
        size_t o = (size_t)(b * K1SEG + s) * (MSZ * DIM) + (size_t)(h * SLEN) * DIM + d;
        #pragma unroll
        for (int j = 0; j < SLEN; ++j)
            M[j] = fmaf(Aseg[o + j * DIM], M[j], Bseg[o + j * DIM]);
    }

    float* MvB = Mv + (size_t)b * (NN + 1) * MSZ * DIM;
    if (seg == 0) {
        #pragma unroll
        for (int j = 0; j < SLEN; ++j)
            MvB[(h * SLEN + j) * DIM + d] = M[j];
    }

    stage1(P, b, t0, tid, q, r, a, Kemb, Vemb, VAemb, Mk, eW, eb, aW, ab);

    // scan: 25 steps, no barriers, rp partials to LDS, Mv streamed out
    for (int tc = 0; tc < SLEN; ++tc) {
        float ev = P[OFF_E + tc * DIM + d], av = P[OFF_A + tc * DIM + d];
        float pr = 0.f;
        #pragma unroll
        for (int j = 0; j < SLEN; ++j) {
            float wj = P[OFF_W + tc * 52 + h * SLEN + j];
            pr = fmaf(wj, M[j], pr);                     // read pre-update
            M[j] = fmaf(wj, fmaf(-M[j], ev, av), M[j]);  // M + w*(a - M*e)
        }
        P[OFF_S + h * 3200 + tc * DIM + d] = pr;
        float* o = MvB + (size_t)(t0 + tc + 1) * (MSZ * DIM) + (size_t)(h * SLEN) * DIM + d;
        #pragma unroll
        for (int j = 0; j < SLEN; ++j) o[j * DIM] = M[j];
    }
    __syncthreads();

    // reads = rp0 + rp1 (into OFF_S)
    for (int idx = tid; idx < SLEN * DIM; idx += 256)
        P[OFF_S + idx] += P[OFF_RP1 + idx];
    __syncthreads();

    // fused phaseC: f = tanh([reads,k]@fW^T + fb); p = sigmoid(f@pW + pb)
    const f4* r4  = (const f4*)(P + OFF_S);
    const f4* k4  = (const f4*)(P + OFF_K);
    const f4* fW4 = (const f4*)fW;
    for (int u = tid; u < SLEN * 16; u += 256) {
        int pos = u >> 4, dg = u & 15, d0 = dg * 8;
        f4 acc[8];
        #pragma unroll
        for (int j = 0; j < 8; ++j) acc[j] = f4{0.f, 0.f, 0.f, 0.f};
        for (int i4 = 0; i4 < 32; ++i4) {
            f4 rv = r4[pos * 32 + i4];
            #pragma unroll
            for (int j = 0; j < 8; ++j)
                acc[j] += rv * fW4[(d0 + j) * 64 + i4];
        }
        for (int i4 = 0; i4 < 32; ++i4) {
            f4 kv = k4[pos * 32 + i4];
            #pragma unroll
            for (int j = 0; j < 8; ++j)
                acc[j] += kv * fW4[(d0 + j) * 64 + 32 + i4];
        }
        float pp = 0.f;
        #pragma unroll
        for (int j = 0; j < 8; ++j) {
            float v = acc[j].x + acc[j].y + acc[j].z + acc[j].w;
            float fv = tanhf(v + fb[d0 + j]);
            pp = fmaf(fv, pW[d0 + j], pp);
        }
        P[OFF_PP + pos * 16 + dg] = pp;
    }
    __syncthreads();
    if (tid < SLEN) {
        float s = 0.f;
        #pragma unroll
        for (int g = 0; g < 16; ++g) s += P[OFF_PP + tid * 16 + g];
        s += pb[0];
        p_out[b * NN + t0 + tid] = 1.f / (1.f + __expf(-s));
    }
}

extern "C" void kernel_launch(void* const* d_in, const int* in_sizes, int n_in,
                              void* d_out, int out_size, void* d_ws, size_t ws_size,
                              hipStream_t stream) {
    const int*   q     = (const int*)d_in[0];
    const int*   r     = (const int*)d_in[1];
    const int*   a     = (const int*)d_in[2];
    const float* Kemb  = (const float*)d_in[3];
    const float* Vemb  = (const float*)d_in[4];
    const float* VAemb = (const float*)d_in[5];
    const float* Mk    = (const float*)d_in[6];
    const float* Mv0   = (const float*)d_in[7];
    const float* fW    = (const float*)d_in[8];
    const float* fb    = (const float*)d_in[9];
    const float* pW    = (const float*)d_in[10];
    const float* pb    = (const float*)d_in[11];
    const float* eW    = (const float*)d_in[12];
    const float* eb    = (const float*)d_in[13];
    const float* aW    = (const float*)d_in[14];
    const float* ab    = (const float*)d_in[15];

    float* p_out = (float*)d_out;
    float* Mv    = p_out + BB * NN;

    float* Aseg = (float*)d_ws;                                  // 448*6400
    float* Bseg = Aseg + (size_t)BB * K1SEG * MSZ * DIM;         // 448*6400

    dkvmn_k1<<<BB * K1SEG, 256, 0, stream>>>(q, r, a, Kemb, Vemb, VAemb, Mk,
                                             eW, eb, aW, ab, Aseg, Bseg);
    dkvmn_k2<<<BB * 8, 256, 0, stream>>>(q, r, a, Kemb, Vemb, VAemb, Mk,
                                         eW, eb, aW, ab, Mv0, Aseg, Bseg,
                                         fW, fb, pW, pb, p_out, Mv);
}

// Round 5
// 204.369 us; speedup vs baseline: 3.3417x; 3.3417x over previous
//
#include <hip/hip_runtime.h>
#include <math.h>

#define NUM_Q_ 10000
#define NUM_A_ 10000
#define DIM 128
#define MSZ 50
#define BB 64
#define NN 200
#define RPOS 8
#define SEG 8
#define SLEN 25
#define K1SEG 7   // only segments 0..6 need aggregates

typedef float f4 __attribute__((ext_vector_type(4)));

// ---------------- Phase A: gather + w(softmax) + e(sigmoid) + ad(tanh) ----------------
__global__ __launch_bounds__(128) void phaseA(
    const int* __restrict__ q, const int* __restrict__ r, const int* __restrict__ a,
    const float* __restrict__ Kemb, const float* __restrict__ Vemb, const float* __restrict__ VAemb,
    const float* __restrict__ Mk, const float* __restrict__ eW, const float* __restrict__ eb,
    const float* __restrict__ aW, const float* __restrict__ ab,
    float* __restrict__ w_ws, float* __restrict__ e_ws, float* __restrict__ ad_ws)
{
    const int tid = threadIdx.x;
    const int pos0 = blockIdx.x * RPOS;
    __shared__ float s_s[RPOS][DIM];
    __shared__ float s_k[RPOS][DIM];

    #pragma unroll
    for (int p = 0; p < RPOS; ++p) {
        int pos = pos0 + p;
        int qi = q[pos], ri = r[pos], ai = a[pos];
        int xi = qi + NUM_Q_ * ri;
        int axi = ai + NUM_A_ * ri;
        s_k[p][tid] = Kemb[(size_t)qi * DIM + tid];
        s_s[p][tid] = Vemb[(size_t)xi * DIM + tid] + VAemb[(size_t)axi * DIM + tid];
    }
    __syncthreads();

    const bool hasM = (tid < MSZ);
    const f4* eWr = (const f4*)(eW + (size_t)tid * DIM);
    const f4* aWr = (const f4*)(aW + (size_t)tid * DIM);
    const f4* mkr = (const f4*)(Mk + (size_t)(hasM ? tid : 0) * DIM);

    f4 ae[RPOS], aa[RPOS], al[RPOS];
    #pragma unroll
    for (int p = 0; p < RPOS; ++p) {
        ae[p] = f4{0.f, 0.f, 0.f, 0.f};
        aa[p] = f4{0.f, 0.f, 0.f, 0.f};
        al[p] = f4{0.f, 0.f, 0.f, 0.f};
    }

    for (int i4 = 0; i4 < DIM / 4; ++i4) {
        f4 we = eWr[i4];
        f4 wa = aWr[i4];
        #pragma unroll
        for (int p = 0; p < RPOS; ++p) {
            f4 sv = ((const f4*)s_s[p])[i4];          // ds_read_b128
            ae[p] += sv * we;
            aa[p] += sv * wa;
        }
        if (hasM) {
            f4 mk = mkr[i4];
            #pragma unroll
            for (int p = 0; p < RPOS; ++p) {
                f4 kv = ((const f4*)s_k[p])[i4];
                al[p] += kv * mk;
            }
        }
    }

    float ebv = eb[tid], abv = ab[tid];
    #pragma unroll
    for (int p = 0; p < RPOS; ++p) {
        float ve = ae[p].x + ae[p].y + ae[p].z + ae[p].w;
        float va = aa[p].x + aa[p].y + aa[p].z + aa[p].w;
        float ev = 1.f / (1.f + __expf(-(ve + ebv)));
        float av = tanhf(va + abv);
        e_ws[(size_t)(pos0 + p) * DIM + tid] = ev;
        ad_ws[(size_t)(pos0 + p) * DIM + tid] = av;
    }

    if (tid < 64) {
        #pragma unroll
        for (int p = 0; p < RPOS; ++p) {
            float lv = hasM ? (al[p].x + al[p].y + al[p].z + al[p].w) : -1e30f;
            float mx = lv;
            #pragma unroll
            for (int off = 32; off >= 1; off >>= 1)
                mx = fmaxf(mx, __shfl_xor(mx, off, 64));
            float ex = hasM ? __expf(lv - mx) : 0.f;
            float sm = ex;
            #pragma unroll
            for (int off = 32; off >= 1; off >>= 1)
                sm += __shfl_xor(sm, off, 64);
            if (hasM) w_ws[(size_t)(pos0 + p) * MSZ + tid] = ex / sm;
        }
    }
}

// ---------------- scanP1: per-segment affine aggregates (A,B) per (m,d) ----------------
// 896 blocks = 64 b x 2 dhalf x 7 seg; 64 threads; lane = d within half.
__global__ __launch_bounds__(64) void scanP1(
    const float* __restrict__ w_ws, const float* __restrict__ e_ws, const float* __restrict__ ad_ws,
    float* __restrict__ Aseg, float* __restrict__ Bseg)
{
    const int bid = blockIdx.x;
    const int b = bid / (2 * K1SEG);
    const int rem = bid - b * 2 * K1SEG;
    const int dc = rem / K1SEG;
    const int seg = rem - dc * K1SEG;
    const int lane = threadIdx.x;
    const int t0 = seg * SLEN;

    __shared__ float w_s[SLEN * 52];
    __shared__ float e_s[SLEN * 64];
    __shared__ float a_s[SLEN * 64];

    const float* wb = w_ws + ((size_t)b * NN + t0) * MSZ;
    const float* eb2 = e_ws + ((size_t)b * NN + t0) * DIM + dc * 64;
    const float* ab2 = ad_ws + ((size_t)b * NN + t0) * DIM + dc * 64;
    for (int k = lane; k < SLEN * MSZ; k += 64) {
        int row = k / MSZ, col = k - row * MSZ;
        w_s[row * 52 + col] = wb[k];
    }
    for (int k = lane; k < SLEN * 64; k += 64) {
        int row = k >> 6, col = k & 63;
        e_s[k] = eb2[row * DIM + col];
        a_s[k] = ab2[row * DIM + col];
    }
    __syncthreads();

    float A[MSZ], Bv[MSZ];
    #pragma unroll
    for (int j = 0; j < MSZ; ++j) { A[j] = 1.f; Bv[j] = 0.f; }

    for (int tc = 0; tc < SLEN; ++tc) {
        float ev = e_s[tc * 64 + lane];
        float av = a_s[tc * 64 + lane];
        const float* wr = &w_s[tc * 52];
        #pragma unroll
        for (int j = 0; j < MSZ; ++j) {
            float wj = wr[j];
            float f = fmaf(-wj, ev, 1.f);
            Bv[j] = fmaf(Bv[j], f, wj * av);
            A[j] *= f;
        }
    }

    float* Ao = Aseg + ((size_t)b * K1SEG + seg) * MSZ * DIM + dc * 64 + lane;
    float* Bo = Bseg + ((size_t)b * K1SEG + seg) * MSZ * DIM + dc * 64 + lane;
    #pragma unroll
    for (int j = 0; j < MSZ; ++j) { Ao[j * DIM] = A[j]; Bo[j * DIM] = Bv[j]; }
}

// ---------------- scanP2: prefix-combine + replay; x4 nontemporal Mv stream ----------------
// 512 blocks x 64 threads. lane: mh = lane>>5 (m-half), dg = lane&31, d0 = 4*dg.
// Thread owns M for m = mh*25+j (j<25) at 4 consecutive d -> all stores dwordx4.
__global__ __launch_bounds__(64) void scanP2(
    const float* __restrict__ Mv0,
    const float* __restrict__ Aseg, const float* __restrict__ Bseg,
    const float* __restrict__ w_ws, const float* __restrict__ e_ws, const float* __restrict__ ad_ws,
    float* __restrict__ rp, float* __restrict__ Mv)
{
    // XCD swizzle: all 8 segments of a batch on one XCD (shared Aseg/Bseg in L2)
    const int P = blockIdx.x;
    const int xcd = P & 7, idx = P >> 3;
    const int b = xcd * 8 + (idx >> 3);
    const int seg = idx & 7;
    const int lane = threadIdx.x;
    const int mh = lane >> 5, dg = lane & 31, d0 = dg * 4;
    const int t0 = seg * SLEN;

    __shared__ float w_s[SLEN * 52];
    __shared__ float e_s[SLEN * DIM];
    __shared__ float a_s[SLEN * DIM];

    const float* wb = w_ws + ((size_t)b * NN + t0) * MSZ;
    for (int k = lane; k < SLEN * MSZ; k += 64) {
        int row = k / MSZ, col = k - row * MSZ;
        w_s[row * 52 + col] = wb[k];
    }
    const float* eb2 = e_ws + ((size_t)b * NN + t0) * DIM;
    const float* ab2 = ad_ws + ((size_t)b * NN + t0) * DIM;
    for (int k = lane; k < SLEN * DIM; k += 64) {   // rows contiguous in t
        e_s[k] = eb2[k];
        a_s[k] = ab2[k];
    }
    __syncthreads();

    // segment-start state via affine prefix combine (registers, f4)
    f4 M4[SLEN];
    #pragma unroll
    for (int j = 0; j < SLEN; ++j)
        M4[j] = ((const f4*)Mv0)[(mh * SLEN + j) * 32 + dg];
    for (int s = 0; s < seg; ++s) {
        const f4* A4 = (const f4*)(Aseg + (size_t)(b * K1SEG + s) * MSZ * DIM);
        const f4* B4 = (const f4*)(Bseg + (size_t)(b * K1SEG + s) * MSZ * DIM);
        #pragma unroll
        for (int j = 0; j < SLEN; ++j) {
            int o = (mh * SLEN + j) * 32 + dg;
            M4[j] = A4[o] * M4[j] + B4[o];
        }
    }

    float* MvB = Mv + (size_t)b * (NN + 1) * MSZ * DIM;
    if (seg == 0) {
        #pragma unroll
        for (int j = 0; j < SLEN; ++j)
            *(f4*)&MvB[(mh * SLEN + j) * DIM + d0] = M4[j];
    }

    float* outBase = MvB + (size_t)(t0 + 1) * MSZ * DIM;
    float* rpo = rp + ((size_t)b * NN + t0) * DIM;

    for (int tc = 0; tc < SLEN; ++tc) {
        f4 e4 = ((const f4*)(e_s + tc * DIM))[dg];
        f4 a4 = ((const f4*)(a_s + tc * DIM))[dg];
        const float* wrow = w_s + tc * 52 + mh * SLEN;
        float* o = outBase + (size_t)tc * MSZ * DIM;
        f4 pr4 = f4{0.f, 0.f, 0.f, 0.f};
        #pragma unroll
        for (int j = 0; j < SLEN; ++j) {
            float wj = wrow[j];                        // LDS broadcast
            pr4 += wj * M4[j];                         // read pre-update
            f4 t1 = a4 - M4[j] * e4;
            M4[j] += wj * t1;                          // M + w*(a - M*e)
            __builtin_nontemporal_store(M4[j], (f4*)&o[(mh * SLEN + j) * DIM + d0]);
        }
        // cross-m-half reduce of the read partials
        pr4.x += __shfl_xor(pr4.x, 32, 64);
        pr4.y += __shfl_xor(pr4.y, 32, 64);
        pr4.z += __shfl_xor(pr4.z, 32, 64);
        pr4.w += __shfl_xor(pr4.w, 32, 64);
        if (mh == 0)
            *(f4*)&rpo[(size_t)tc * DIM + d0] = pr4;
    }
}

// ---------------- Phase C: f = tanh([reads,k]@fW^T+fb), p = sigmoid(f@pW+pb) ----------------
__global__ __launch_bounds__(128) void phaseC(
    const int* __restrict__ q, const float* __restrict__ Kemb,
    const float* __restrict__ rp,
    const float* __restrict__ fW, const float* __restrict__ fb,
    const float* __restrict__ pW, const float* __restrict__ pb,
    float* __restrict__ p_out)
{
    const int tid = threadIdx.x;
    const int pos0 = blockIdx.x * RPOS;
    __shared__ float s_cat[RPOS][2 * DIM];
    __shared__ float part[2][RPOS];

    #pragma unroll
    for (int p = 0; p < RPOS; ++p) {
        int pos = pos0 + p;
        s_cat[p][tid] = rp[(size_t)pos * DIM + tid];
        s_cat[p][DIM + tid] = Kemb[(size_t)q[pos] * DIM + tid];
    }
    __syncthreads();

    const f4* fWr = (const f4*)(fW + (size_t)tid * 2 * DIM);
    f4 acc4[RPOS];
    #pragma unroll
    for (int p = 0; p < RPOS; ++p) acc4[p] = f4{0.f, 0.f, 0.f, 0.f};

    for (int i4 = 0; i4 < (2 * DIM) / 4; ++i4) {
        f4 wf = fWr[i4];
        #pragma unroll
        for (int p = 0; p < RPOS; ++p) {
            f4 cv = ((const f4*)s_cat[p])[i4];        // ds_read_b128
            acc4[p] += cv * wf;
        }
    }

    float fbv = fb[tid], pwv = pW[tid];
    const int wv = tid >> 6, ln = tid & 63;
    #pragma unroll
    for (int p = 0; p < RPOS; ++p) {
        float s = acc4[p].x + acc4[p].y + acc4[p].z + acc4[p].w;
        float v = tanhf(s + fbv) * pwv;
        #pragma unroll
        for (int off = 32; off >= 1; off >>= 1)
            v += __shfl_xor(v, off, 64);
        if (ln == 0) part[wv][p] = v;
    }
    __syncthreads();
    if (tid < RPOS) {
        float pv = part[0][tid] + part[1][tid] + pb[0];
        p_out[pos0 + tid] = 1.f / (1.f + __expf(-pv));
    }
}

extern "C" void kernel_launch(void* const* d_in, const int* in_sizes, int n_in,
                              void* d_out, int out_size, void* d_ws, size_t ws_size,
                              hipStream_t stream) {
    const int*   q     = (const int*)d_in[0];
    const int*   r     = (const int*)d_in[1];
    const int*   a     = (const int*)d_in[2];
    const float* Kemb  = (const float*)d_in[3];
    const float* Vemb  = (const float*)d_in[4];
    const float* VAemb = (const float*)d_in[5];
    const float* Mk    = (const float*)d_in[6];
    const float* Mv0   = (const float*)d_in[7];
    const float* fW    = (const float*)d_in[8];
    const float* fb    = (const float*)d_in[9];
    const float* pW    = (const float*)d_in[10];
    const float* pb    = (const float*)d_in[11];
    const float* eW    = (const float*)d_in[12];
    const float* eb    = (const float*)d_in[13];
    const float* aW    = (const float*)d_in[14];
    const float* ab    = (const float*)d_in[15];

    float* p_out = (float*)d_out;
    float* Mv    = p_out + BB * NN;

    float* ws    = (float*)d_ws;
    float* w_ws  = ws;                                    // B*N*50
    float* e_ws  = w_ws + (size_t)BB * NN * MSZ;          // B*N*128
    float* ad_ws = e_ws + (size_t)BB * NN * DIM;          // B*N*128
    float* rp    = ad_ws + (size_t)BB * NN * DIM;         // B*N*128
    float* Aseg  = rp + (size_t)BB * NN * DIM;            // B*7*50*128
    float* Bseg  = Aseg + (size_t)BB * K1SEG * MSZ * DIM; // B*7*50*128

    phaseA<<<BB * NN / RPOS, 128, 0, stream>>>(q, r, a, Kemb, Vemb, VAemb,
                                               Mk, eW, eb, aW, ab,
                                               w_ws, e_ws, ad_ws);
    scanP1<<<BB * 2 * K1SEG, 64, 0, stream>>>(w_ws, e_ws, ad_ws, Aseg, Bseg);
    scanP2<<<BB * SEG, 64, 0, stream>>>(Mv0, Aseg, Bseg, w_ws, e_ws, ad_ws, rp, Mv);
    phaseC<<<BB * NN / RPOS, 128, 0, stream>>>(q, Kemb, rp, fW, fb, pW, pb, p_out);
}

// Round 6
// 185.169 us; speedup vs baseline: 3.6882x; 1.1037x over previous
//
#include <hip/hip_runtime.h>
#include <math.h>

#define NUM_Q_ 10000
#define NUM_A_ 10000
#define DIM 128
#define MSZ 50
#define BB 64
#define NN 200
#define SEG 8
#define SLEN 25
#define K1SEG 7
#define RPOS 8

typedef float f4 __attribute__((ext_vector_type(4)));

__device__ __forceinline__ float hadd(f4 v) { return (v.x + v.y) + (v.z + v.w); }
// m -> padded slot in [25][64] w layout (halves at 0 and 32, 25 used + 7 zero pad)
__device__ __forceinline__ int wslot(int m) { return m + (m >= 25 ? 7 : 0); }

// ============ K_A: gather + e/ad/logit GEMVs + softmax + segment affine aggregates ============
// grid 512 = (b, seg); 256 threads (4 waves). Wave w owns positions [pw0, pw0+npw).
// Thread owns 5 output cols: e[lane], e[lane+64], ad[lane], ad[lane+64], logit m=lane(<50).
__global__ __launch_bounds__(256, 2) void kernA(
    const int* __restrict__ q, const int* __restrict__ r, const int* __restrict__ a,
    const float* __restrict__ Kemb, const float* __restrict__ Vemb, const float* __restrict__ VAemb,
    const float* __restrict__ Mk, const float* __restrict__ eW, const float* __restrict__ eb,
    const float* __restrict__ aW, const float* __restrict__ ab,
    float* __restrict__ w_ws, float* __restrict__ e_ws, float* __restrict__ ad_ws,
    float* __restrict__ Aseg, float* __restrict__ Bseg)
{
    __shared__ float s_s[SLEN * DIM];
    __shared__ float s_k[SLEN * DIM];
    __shared__ float w_s[SLEN * 64];
    __shared__ float e_s[SLEN * DIM];
    __shared__ float a_s[SLEN * DIM];
    __shared__ int   idxs[3 * 32];

    const int bid = blockIdx.x;
    const int b = bid >> 3, seg = bid & 7;
    const int t0 = seg * SLEN;
    const int tid = threadIdx.x;
    const int lane = tid & 63, wv = tid >> 6;

    if (tid < SLEN) {
        int pos = b * NN + t0 + tid;
        int qi = q[pos], ri = r[pos], ai = a[pos];
        idxs[tid]      = qi;
        idxs[32 + tid] = qi + NUM_Q_ * ri;
        idxs[64 + tid] = ai + NUM_A_ * ri;
    }
    // zero w pad slots while we're here
    for (int k = tid; k < SLEN * 64; k += 256) w_s[k] = 0.f;
    __syncthreads();

    for (int k = tid; k < SLEN * DIM; k += 256) {
        int pl = k >> 7, dc = k & 127;
        s_k[k] = Kemb[(size_t)idxs[pl] * DIM + dc];
        s_s[k] = Vemb[(size_t)idxs[32 + pl] * DIM + dc]
               + VAemb[(size_t)idxs[64 + pl] * DIM + dc];
    }
    __syncthreads();

    // ---- GEMV: 5 cols/thread, f4-broadcast of s/k feeds 5 f4-FMAs ----
    const int pw0 = (wv == 0) ? 0 : 7 + 6 * (wv - 1);   // 0,7,13,19
    const int npw = (wv == 0) ? 7 : 6;

    f4 ac0[7], ac1[7], ac2[7], ac3[7], acl[7];
    #pragma unroll
    for (int p = 0; p < 7; ++p) {
        ac0[p] = f4{0,0,0,0}; ac1[p] = f4{0,0,0,0}; ac2[p] = f4{0,0,0,0};
        ac3[p] = f4{0,0,0,0}; acl[p] = f4{0,0,0,0};
    }

    const f4* W0 = (const f4*)(eW + (size_t)lane * DIM);
    const f4* W1 = (const f4*)(eW + (size_t)(lane + 64) * DIM);
    const f4* W2 = (const f4*)(aW + (size_t)lane * DIM);
    const f4* W3 = (const f4*)(aW + (size_t)(lane + 64) * DIM);
    const f4* WM = (const f4*)(Mk + (size_t)(lane < MSZ ? lane : 0) * DIM);

    for (int i4 = 0; i4 < 32; ++i4) {
        f4 w0 = W0[i4], w1 = W1[i4], w2 = W2[i4], w3 = W3[i4], wm = WM[i4];
        #pragma unroll
        for (int p = 0; p < 7; ++p) {
            if (p < npw) {
                int pos = pw0 + p;
                f4 s4 = *(const f4*)&s_s[pos * DIM + i4 * 4];   // LDS b128 broadcast
                f4 k4 = *(const f4*)&s_k[pos * DIM + i4 * 4];
                ac0[p] += w0 * s4;
                ac1[p] += w1 * s4;
                ac2[p] += w2 * s4;
                ac3[p] += w3 * s4;
                acl[p] += wm * k4;
            }
        }
    }

    const float eb0 = eb[lane], eb1 = eb[lane + 64];
    const float ab0 = ab[lane], ab1 = ab[lane + 64];
    #pragma unroll
    for (int p = 0; p < 7; ++p) {
        if (p < npw) {
            int pos = pw0 + p;
            size_t g = (size_t)(b * NN + t0 + pos) * DIM;
            float v0 = 1.f / (1.f + __expf(-(hadd(ac0[p]) + eb0)));
            float v1 = 1.f / (1.f + __expf(-(hadd(ac1[p]) + eb1)));
            float v2 = tanhf(hadd(ac2[p]) + ab0);
            float v3 = tanhf(hadd(ac3[p]) + ab1);
            e_s[pos * DIM + lane] = v0;        e_ws[g + lane] = v0;
            e_s[pos * DIM + lane + 64] = v1;   e_ws[g + lane + 64] = v1;
            a_s[pos * DIM + lane] = v2;        ad_ws[g + lane] = v2;
            a_s[pos * DIM + lane + 64] = v3;   ad_ws[g + lane + 64] = v3;
            if (lane < MSZ) w_s[pos * 64 + wslot(lane)] = hadd(acl[p]);
        }
    }
    __syncthreads();

    // ---- softmax over m (one position per thread) + write w_ws ----
    if (tid < SLEN) {
        float mx = -1e30f;
        #pragma unroll
        for (int m = 0; m < MSZ; ++m) mx = fmaxf(mx, w_s[tid * 64 + wslot(m)]);
        float sm = 0.f;
        float ex[MSZ];
        #pragma unroll
        for (int m = 0; m < MSZ; ++m) {
            ex[m] = __expf(w_s[tid * 64 + wslot(m)] - mx);
            sm += ex[m];
        }
        float inv = 1.f / sm;
        size_t g = (size_t)(b * NN + t0 + tid) * MSZ;
        #pragma unroll
        for (int m = 0; m < MSZ; ++m) {
            float wv2 = ex[m] * inv;
            w_s[tid * 64 + wslot(m)] = wv2;
            w_ws[g + m] = wv2;
        }
    }
    __syncthreads();

    // ---- segment affine aggregate (only segs 0..6 needed) ----
    if (seg < K1SEG) {
        const int d = tid & 127, mh = tid >> 7;
        float A[28], Bv[28];
        #pragma unroll
        for (int j = 0; j < 28; ++j) { A[j] = 1.f; Bv[j] = 0.f; }
        for (int tc = 0; tc < SLEN; ++tc) {
            float ev = e_s[tc * DIM + d], av = a_s[tc * DIM + d];
            #pragma unroll
            for (int g = 0; g < 7; ++g) {
                f4 w4 = *(const f4*)&w_s[tc * 64 + mh * 32 + g * 4];
                #pragma unroll
                for (int c = 0; c < 4; ++c) {
                    int j = g * 4 + c;
                    float wj = w4[c];
                    float f = fmaf(-wj, ev, 1.f);
                    Bv[j] = fmaf(Bv[j], f, wj * av);
                    A[j] *= f;
                }
            }
        }
        size_t base = (size_t)(b * K1SEG + seg) * (MSZ * DIM) + (size_t)(mh * SLEN) * DIM + d;
        #pragma unroll
        for (int j = 0; j < SLEN; ++j) {
            Aseg[base + j * DIM] = A[j];
            Bseg[base + j * DIM] = Bv[j];
        }
    }
}

// ============ K_B: prefix-combine + scan replay; 2048 blocks (b,seg,dq) x 64 thr ============
__global__ __launch_bounds__(64, 2) void kernB(
    const float* __restrict__ Mv0,
    const float* __restrict__ Aseg, const float* __restrict__ Bseg,
    const float* __restrict__ w_ws, const float* __restrict__ e_ws, const float* __restrict__ ad_ws,
    float* __restrict__ rp, float* __restrict__ Mv)
{
    // XCD swizzle: 256 consecutive logical blocks (8 full batches) per XCD
    const int bid = blockIdx.x;
    const int lg = (bid & 7) * 256 + (bid >> 3);
    const int b = lg >> 5, seg = (lg >> 2) & 7, dq = lg & 3;
    const int lane = threadIdx.x;
    const int dg = lane & 31, mh = lane >> 5;
    const int d = dq * 32 + dg;
    const int t0 = seg * SLEN;

    __shared__ float w_s[SLEN * 64];
    __shared__ float e_s[SLEN * 32];
    __shared__ float a_s[SLEN * 32];

    for (int k = lane; k < SLEN * 64; k += 64) {
        int row = k >> 6, slot = k & 63, sl = slot & 31;
        float v = 0.f;
        if (sl < SLEN) {
            int m = (slot < 32) ? slot : slot - 7;
            v = w_ws[(size_t)(b * NN + t0 + row) * MSZ + m];
        }
        w_s[k] = v;
    }
    for (int k = lane; k < SLEN * 32; k += 64) {
        int row = k >> 5, c = k & 31;
        size_t g = (size_t)(b * NN + t0 + row) * DIM + dq * 32 + c;
        e_s[k] = e_ws[g];
        a_s[k] = ad_ws[g];
    }
    __syncthreads();

    float M[28];
    #pragma unroll
    for (int j = 0; j < 28; ++j)
        M[j] = (j < SLEN) ? Mv0[(mh * SLEN + j) * DIM + d] : 0.f;

    for (int s = 0; s < seg; ++s) {
        size_t base = (size_t)(b * K1SEG + s) * (MSZ * DIM) + (size_t)(mh * SLEN) * DIM + d;
        #pragma unroll
        for (int j = 0; j < SLEN; ++j)
            M[j] = fmaf(Aseg[base + j * DIM], M[j], Bseg[base + j * DIM]);
    }

    float* MvB = Mv + (size_t)b * (NN + 1) * MSZ * DIM;
    if (seg == 0) {
        #pragma unroll
        for (int j = 0; j < SLEN; ++j)
            MvB[(mh * SLEN + j) * DIM + d] = M[j];
    }

    float* out = MvB + (size_t)(t0 + 1) * MSZ * DIM;
    float* rpo = rp + ((size_t)(b * NN + t0)) * DIM + d;

    for (int tc = 0; tc < SLEN; ++tc) {
        float ev = e_s[tc * 32 + dg], av = a_s[tc * 32 + dg];
        f4 w4[7];
        #pragma unroll
        for (int g = 0; g < 7; ++g)
            w4[g] = *(const f4*)&w_s[tc * 64 + mh * 32 + g * 4];
        float pr = 0.f;
        #pragma unroll
        for (int j = 0; j < 28; ++j) {
            float wj = w4[j >> 2][j & 3];       // pads are 0 -> inert
            pr = fmaf(wj, M[j], pr);            // read pre-update memory
            M[j] = fmaf(wj, fmaf(-M[j], ev, av), M[j]);
        }
        float* o = out + (size_t)tc * MSZ * DIM;
        #pragma unroll
        for (int j = 0; j < SLEN; ++j)
            o[(mh * SLEN + j) * DIM + d] = M[j];
        pr += __shfl_xor(pr, 32, 64);
        if (mh == 0) rpo[(size_t)tc * DIM] = pr;
    }
}

// ============ K_C: f = tanh([reads,k]@fW^T+fb), p = sigmoid(f@pW+pb) ============
__global__ __launch_bounds__(128) void kernC(
    const int* __restrict__ q, const float* __restrict__ Kemb,
    const float* __restrict__ rp,
    const float* __restrict__ fW, const float* __restrict__ fb,
    const float* __restrict__ pW, const float* __restrict__ pb,
    float* __restrict__ p_out)
{
    const int tid = threadIdx.x;
    const int pos0 = blockIdx.x * RPOS;
    __shared__ float s_cat[RPOS][2 * DIM];
    __shared__ float part[2][RPOS];

    #pragma unroll
    for (int p = 0; p < RPOS; ++p) {
        int pos = pos0 + p;
        s_cat[p][tid] = rp[(size_t)pos * DIM + tid];
        s_cat[p][DIM + tid] = Kemb[(size_t)q[pos] * DIM + tid];
    }
    __syncthreads();

    const f4* fWr = (const f4*)(fW + (size_t)tid * 2 * DIM);
    f4 acc4[RPOS];
    #pragma unroll
    for (int p = 0; p < RPOS; ++p) acc4[p] = f4{0,0,0,0};

    for (int i4 = 0; i4 < (2 * DIM) / 4; ++i4) {
        f4 wf = fWr[i4];
        #pragma unroll
        for (int p = 0; p < RPOS; ++p)
            acc4[p] += ((const f4*)s_cat[p])[i4] * wf;
    }

    float fbv = fb[tid], pwv = pW[tid];
    const int wv = tid >> 6, ln = tid & 63;
    #pragma unroll
    for (int p = 0; p < RPOS; ++p) {
        float v = tanhf(hadd(acc4[p]) + fbv) * pwv;
        #pragma unroll
        for (int off = 32; off >= 1; off >>= 1)
            v += __shfl_xor(v, off, 64);
        if (ln == 0) part[wv][p] = v;
    }
    __syncthreads();
    if (tid < RPOS) {
        float pv = part[0][tid] + part[1][tid] + pb[0];
        p_out[pos0 + tid] = 1.f / (1.f + __expf(-pv));
    }
}

extern "C" void kernel_launch(void* const* d_in, const int* in_sizes, int n_in,
                              void* d_out, int out_size, void* d_ws, size_t ws_size,
                              hipStream_t stream) {
    const int*   q     = (const int*)d_in[0];
    const int*   r     = (const int*)d_in[1];
    const int*   a     = (const int*)d_in[2];
    const float* Kemb  = (const float*)d_in[3];
    const float* Vemb  = (const float*)d_in[4];
    const float* VAemb = (const float*)d_in[5];
    const float* Mk    = (const float*)d_in[6];
    const float* Mv0   = (const float*)d_in[7];
    const float* fW    = (const float*)d_in[8];
    const float* fb    = (const float*)d_in[9];
    const float* pW    = (const float*)d_in[10];
    const float* pb    = (const float*)d_in[11];
    const float* eW    = (const float*)d_in[12];
    const float* eb    = (const float*)d_in[13];
    const float* aW    = (const float*)d_in[14];
    const float* ab    = (const float*)d_in[15];

    float* p_out = (float*)d_out;
    float* Mv    = p_out + BB * NN;

    float* ws    = (float*)d_ws;
    float* w_ws  = ws;                                      // B*N*50
    float* e_ws  = w_ws + (size_t)BB * NN * MSZ;            // B*N*128
    float* ad_ws = e_ws + (size_t)BB * NN * DIM;            // B*N*128
    float* rp    = ad_ws + (size_t)BB * NN * DIM;           // B*N*128
    float* Aseg  = rp + (size_t)BB * NN * DIM;              // B*7*50*128
    float* Bseg  = Aseg + (size_t)BB * K1SEG * MSZ * DIM;   // B*7*50*128

    kernA<<<BB * SEG, 256, 0, stream>>>(q, r, a, Kemb, Vemb, VAemb, Mk,
                                        eW, eb, aW, ab,
                                        w_ws, e_ws, ad_ws, Aseg, Bseg);
    kernB<<<BB * SEG * 4, 64, 0, stream>>>(Mv0, Aseg, Bseg, w_ws, e_ws, ad_ws, rp, Mv);
    kernC<<<BB * NN / RPOS, 128, 0, stream>>>(q, Kemb, rp, fW, fb, pW, pb, p_out);
}

// Round 7
// 179.664 us; speedup vs baseline: 3.8013x; 1.0306x over previous
//
#include <hip/hip_runtime.h>
#include <math.h>

#define NUM_Q_ 10000
#define NUM_A_ 10000
#define DIM 128
#define MSZ 50
#define BB 64
#define NN 200
#define SEG 8
#define SLEN 25
#define K1SEG 7
#define RPOS 8

typedef float f4 __attribute__((ext_vector_type(4)));

__device__ __forceinline__ float hadd(f4 v) { return (v.x + v.y) + (v.z + v.w); }
// m -> padded slot in [25][64] w layout (halves at 0 and 32, 25 used + 7 zero pad)
__device__ __forceinline__ int wslot(int m) { return m + (m >= 25 ? 7 : 0); }

// ============ K_A: gather + e/ad/logit GEMVs + softmax + segment affine aggregates ============
// grid 512: bid = seg*64 + b  (b -> XCD affinity: xcd = b%8). 256 threads (4 waves).
__global__ __launch_bounds__(256, 2) void kernA(
    const int* __restrict__ q, const int* __restrict__ r, const int* __restrict__ a,
    const float* __restrict__ Kemb, const float* __restrict__ Vemb, const float* __restrict__ VAemb,
    const float* __restrict__ Mk, const float* __restrict__ eW, const float* __restrict__ eb,
    const float* __restrict__ aW, const float* __restrict__ ab,
    float* __restrict__ w_ws, float* __restrict__ e_ws, float* __restrict__ ad_ws,
    float* __restrict__ Aseg, float* __restrict__ Bseg)
{
    __shared__ float s_s[SLEN * DIM];
    __shared__ float s_k[SLEN * DIM];
    __shared__ float w_s[SLEN * 64];
    __shared__ float e_s[SLEN * DIM];
    __shared__ float a_s[SLEN * DIM];
    __shared__ int   idxs[3 * 32];

    const int bid = blockIdx.x;
    const int b = bid & 63, seg = bid >> 6;
    const int t0 = seg * SLEN;
    const int tid = threadIdx.x;
    const int lane = tid & 63, wv = tid >> 6;

    if (tid < SLEN) {
        int pos = b * NN + t0 + tid;
        int qi = q[pos], ri = r[pos], ai = a[pos];
        idxs[tid]      = qi;
        idxs[32 + tid] = qi + NUM_Q_ * ri;
        idxs[64 + tid] = ai + NUM_A_ * ri;
    }
    for (int k = tid; k < SLEN * 64; k += 256) w_s[k] = 0.f;
    __syncthreads();

    for (int k = tid; k < SLEN * DIM; k += 256) {
        int pl = k >> 7, dc = k & 127;
        s_k[k] = Kemb[(size_t)idxs[pl] * DIM + dc];
        s_s[k] = Vemb[(size_t)idxs[32 + pl] * DIM + dc]
               + VAemb[(size_t)idxs[64 + pl] * DIM + dc];
    }
    __syncthreads();

    // ---- GEMV: 5 cols/thread, f4-broadcast of s/k feeds 5 f4-FMAs ----
    const int pw0 = (wv == 0) ? 0 : 7 + 6 * (wv - 1);   // 0,7,13,19
    const int npw = (wv == 0) ? 7 : 6;

    f4 ac0[7], ac1[7], ac2[7], ac3[7], acl[7];
    #pragma unroll
    for (int p = 0; p < 7; ++p) {
        ac0[p] = f4{0,0,0,0}; ac1[p] = f4{0,0,0,0}; ac2[p] = f4{0,0,0,0};
        ac3[p] = f4{0,0,0,0}; acl[p] = f4{0,0,0,0};
    }

    const f4* W0 = (const f4*)(eW + (size_t)lane * DIM);
    const f4* W1 = (const f4*)(eW + (size_t)(lane + 64) * DIM);
    const f4* W2 = (const f4*)(aW + (size_t)lane * DIM);
    const f4* W3 = (const f4*)(aW + (size_t)(lane + 64) * DIM);
    const f4* WM = (const f4*)(Mk + (size_t)(lane < MSZ ? lane : 0) * DIM);

    for (int i4 = 0; i4 < 32; ++i4) {
        f4 w0 = W0[i4], w1 = W1[i4], w2 = W2[i4], w3 = W3[i4], wm = WM[i4];
        #pragma unroll
        for (int p = 0; p < 7; ++p) {
            if (p < npw) {
                int pos = pw0 + p;
                f4 s4 = *(const f4*)&s_s[pos * DIM + i4 * 4];
                f4 k4 = *(const f4*)&s_k[pos * DIM + i4 * 4];
                ac0[p] += w0 * s4;
                ac1[p] += w1 * s4;
                ac2[p] += w2 * s4;
                ac3[p] += w3 * s4;
                acl[p] += wm * k4;
            }
        }
    }

    const float eb0 = eb[lane], eb1 = eb[lane + 64];
    const float ab0 = ab[lane], ab1 = ab[lane + 64];
    #pragma unroll
    for (int p = 0; p < 7; ++p) {
        if (p < npw) {
            int pos = pw0 + p;
            size_t g = (size_t)(b * NN + t0 + pos) * DIM;
            float v0 = 1.f / (1.f + __expf(-(hadd(ac0[p]) + eb0)));
            float v1 = 1.f / (1.f + __expf(-(hadd(ac1[p]) + eb1)));
            float v2 = tanhf(hadd(ac2[p]) + ab0);
            float v3 = tanhf(hadd(ac3[p]) + ab1);
            e_s[pos * DIM + lane] = v0;        e_ws[g + lane] = v0;
            e_s[pos * DIM + lane + 64] = v1;   e_ws[g + lane + 64] = v1;
            a_s[pos * DIM + lane] = v2;        ad_ws[g + lane] = v2;
            a_s[pos * DIM + lane + 64] = v3;   ad_ws[g + lane + 64] = v3;
            if (lane < MSZ) w_s[pos * 64 + wslot(lane)] = hadd(acl[p]);
        }
    }
    __syncthreads();

    if (tid < SLEN) {
        float mx = -1e30f;
        #pragma unroll
        for (int m = 0; m < MSZ; ++m) mx = fmaxf(mx, w_s[tid * 64 + wslot(m)]);
        float sm = 0.f;
        float ex[MSZ];
        #pragma unroll
        for (int m = 0; m < MSZ; ++m) {
            ex[m] = __expf(w_s[tid * 64 + wslot(m)] - mx);
            sm += ex[m];
        }
        float inv = 1.f / sm;
        size_t g = (size_t)(b * NN + t0 + tid) * MSZ;
        #pragma unroll
        for (int m = 0; m < MSZ; ++m) {
            float wv2 = ex[m] * inv;
            w_s[tid * 64 + wslot(m)] = wv2;
            w_ws[g + m] = wv2;
        }
    }
    __syncthreads();

    if (seg < K1SEG) {
        const int d = tid & 127, mh = tid >> 7;
        float A[28], Bv[28];
        #pragma unroll
        for (int j = 0; j < 28; ++j) { A[j] = 1.f; Bv[j] = 0.f; }
        for (int tc = 0; tc < SLEN; ++tc) {
            float ev = e_s[tc * DIM + d], av = a_s[tc * DIM + d];
            #pragma unroll
            for (int g = 0; g < 7; ++g) {
                f4 w4 = *(const f4*)&w_s[tc * 64 + mh * 32 + g * 4];
                #pragma unroll
                for (int c = 0; c < 4; ++c) {
                    int j = g * 4 + c;
                    float wj = w4[c];
                    float f = fmaf(-wj, ev, 1.f);
                    Bv[j] = fmaf(Bv[j], f, wj * av);
                    A[j] *= f;
                }
            }
        }
        size_t base = (size_t)(b * K1SEG + seg) * (MSZ * DIM) + (size_t)(mh * SLEN) * DIM + d;
        #pragma unroll
        for (int j = 0; j < SLEN; ++j) {
            Aseg[base + j * DIM] = A[j];
            Bseg[base + j * DIM] = Bv[j];
        }
    }
}

// ============ K_B: prefix-combine + scan; full-row contiguous Mv stores ============
// grid 512: bid = seg*64 + b. 256 threads: tid = mh*128 + d. Per (tc,j) the block
// writes one full [50][128] slab row-pair; slabs are tc-consecutive (fill-shaped).
__global__ __launch_bounds__(256, 2) void kernB(
    const float* __restrict__ Mv0,
    const float* __restrict__ Aseg, const float* __restrict__ Bseg,
    const float* __restrict__ w_ws, const float* __restrict__ e_ws, const float* __restrict__ ad_ws,
    float* __restrict__ rp, float* __restrict__ Mv)
{
    const int bid = blockIdx.x;
    const int b = bid & 63, seg = bid >> 6;
    const int tid = threadIdx.x;
    const int d = tid & 127, mh = tid >> 7;
    const int t0 = seg * SLEN;

    __shared__ float w_s[SLEN * 56];    // [25][2*28], 25 used + 3 zero pad per half
    __shared__ float e_s[SLEN * DIM];
    __shared__ float a_s[SLEN * DIM];
    __shared__ float rp_s[SLEN * 256];  // [25][2][128] partials

    for (int k = tid; k < SLEN * 56; k += 256) {
        int row = k / 56, slot = k - row * 56;
        int hh = slot / 28, j = slot - hh * 28;
        float v = 0.f;
        if (j < SLEN) v = w_ws[(size_t)(b * NN + t0 + row) * MSZ + hh * SLEN + j];
        w_s[k] = v;
    }
    for (int k = tid; k < SLEN * DIM; k += 256) {
        int row = k >> 7, c = k & 127;
        size_t g = (size_t)(b * NN + t0 + row) * DIM + c;
        e_s[k] = e_ws[g];
        a_s[k] = ad_ws[g];
    }
    __syncthreads();

    float M[SLEN];
    #pragma unroll
    for (int j = 0; j < SLEN; ++j) M[j] = Mv0[(mh * SLEN + j) * DIM + d];

    for (int s = 0; s < seg; ++s) {
        size_t base = (size_t)(b * K1SEG + s) * (MSZ * DIM) + (size_t)(mh * SLEN) * DIM + d;
        #pragma unroll
        for (int j = 0; j < SLEN; ++j)
            M[j] = fmaf(Aseg[base + j * DIM], M[j], Bseg[base + j * DIM]);
    }

    float* MvB = Mv + (size_t)b * (NN + 1) * MSZ * DIM;
    if (seg == 0) {
        #pragma unroll
        for (int j = 0; j < SLEN; ++j)
            MvB[(mh * SLEN + j) * DIM + d] = M[j];
    }
    float* out = MvB + (size_t)(t0 + 1) * MSZ * DIM + (size_t)(mh * SLEN) * DIM + d;

    for (int tc = 0; tc < SLEN; ++tc) {
        float ev = e_s[tc * DIM + d], av = a_s[tc * DIM + d];
        f4 w4[7];
        #pragma unroll
        for (int g = 0; g < 7; ++g)
            w4[g] = *(const f4*)&w_s[tc * 56 + mh * 28 + g * 4];
        float pr = 0.f;
        float* o = out + (size_t)tc * MSZ * DIM;
        #pragma unroll
        for (int j = 0; j < SLEN; ++j) {
            float wj = w4[j >> 2][j & 3];
            pr = fmaf(wj, M[j], pr);                       // read pre-update memory
            M[j] = fmaf(wj, fmaf(-M[j], ev, av), M[j]);    // M + w*(a - M*e)
            __builtin_nontemporal_store(M[j], &o[j * DIM]);
        }
        rp_s[tc * 256 + mh * 128 + d] = pr;
    }
    __syncthreads();

    float* rpo = rp + (size_t)(b * NN + t0) * DIM;
    for (int k = tid; k < SLEN * DIM; k += 256) {
        int row = k >> 7, c = k & 127;
        rpo[(size_t)row * DIM + c] = rp_s[row * 256 + c] + rp_s[row * 256 + 128 + c];
    }
}

// ============ K_C: f = tanh([reads,k]@fW^T+fb), p = sigmoid(f@pW+pb) ============
// grid 1600: bid = g*64 + b (g = 8-position group), XCD-affine with producer.
__global__ __launch_bounds__(128) void kernC(
    const int* __restrict__ q, const float* __restrict__ Kemb,
    const float* __restrict__ rp,
    const float* __restrict__ fW, const float* __restrict__ fb,
    const float* __restrict__ pW, const float* __restrict__ pb,
    float* __restrict__ p_out)
{
    const int bid = blockIdx.x;
    const int b = bid & 63, grp = bid >> 6;
    const int tid = threadIdx.x;
    const int pos0 = b * NN + grp * RPOS;
    __shared__ float s_cat[RPOS][2 * DIM];
    __shared__ float part[2][RPOS];

    #pragma unroll
    for (int p = 0; p < RPOS; ++p) {
        int pos = pos0 + p;
        s_cat[p][tid] = rp[(size_t)pos * DIM + tid];
        s_cat[p][DIM + tid] = Kemb[(size_t)q[pos] * DIM + tid];
    }
    __syncthreads();

    const f4* fWr = (const f4*)(fW + (size_t)tid * 2 * DIM);
    f4 acc4[RPOS];
    #pragma unroll
    for (int p = 0; p < RPOS; ++p) acc4[p] = f4{0,0,0,0};

    for (int i4 = 0; i4 < (2 * DIM) / 4; ++i4) {
        f4 wf = fWr[i4];
        #pragma unroll
        for (int p = 0; p < RPOS; ++p)
            acc4[p] += ((const f4*)s_cat[p])[i4] * wf;
    }

    float fbv = fb[tid], pwv = pW[tid];
    const int wv = tid >> 6, ln = tid & 63;
    #pragma unroll
    for (int p = 0; p < RPOS; ++p) {
        float v = tanhf(hadd(acc4[p]) + fbv) * pwv;
        #pragma unroll
        for (int off = 32; off >= 1; off >>= 1)
            v += __shfl_xor(v, off, 64);
        if (ln == 0) part[wv][p] = v;
    }
    __syncthreads();
    if (tid < RPOS) {
        float pv = part[0][tid] + part[1][tid] + pb[0];
        p_out[pos0 + tid] = 1.f / (1.f + __expf(-pv));
    }
}

extern "C" void kernel_launch(void* const* d_in, const int* in_sizes, int n_in,
                              void* d_out, int out_size, void* d_ws, size_t ws_size,
                              hipStream_t stream) {
    const int*   q     = (const int*)d_in[0];
    const int*   r     = (const int*)d_in[1];
    const int*   a     = (const int*)d_in[2];
    const float* Kemb  = (const float*)d_in[3];
    const float* Vemb  = (const float*)d_in[4];
    const float* VAemb = (const float*)d_in[5];
    const float* Mk    = (const float*)d_in[6];
    const float* Mv0   = (const float*)d_in[7];
    const float* fW    = (const float*)d_in[8];
    const float* fb    = (const float*)d_in[9];
    const float* pW    = (const float*)d_in[10];
    const float* pb    = (const float*)d_in[11];
    const float* eW    = (const float*)d_in[12];
    const float* eb    = (const float*)d_in[13];
    const float* aW    = (const float*)d_in[14];
    const float* ab    = (const float*)d_in[15];

    float* p_out = (float*)d_out;
    float* Mv    = p_out + BB * NN;

    float* ws    = (float*)d_ws;
    float* w_ws  = ws;                                      // B*N*50
    float* e_ws  = w_ws + (size_t)BB * NN * MSZ;            // B*N*128
    float* ad_ws = e_ws + (size_t)BB * NN * DIM;            // B*N*128
    float* rp    = ad_ws + (size_t)BB * NN * DIM;           // B*N*128
    float* Aseg  = rp + (size_t)BB * NN * DIM;              // B*7*50*128
    float* Bseg  = Aseg + (size_t)BB * K1SEG * MSZ * DIM;   // B*7*50*128

    kernA<<<BB * SEG, 256, 0, stream>>>(q, r, a, Kemb, Vemb, VAemb, Mk,
                                        eW, eb, aW, ab,
                                        w_ws, e_ws, ad_ws, Aseg, Bseg);
    kernB<<<BB * SEG, 256, 0, stream>>>(Mv0, Aseg, Bseg, w_ws, e_ws, ad_ws, rp, Mv);
    kernC<<<BB * NN / RPOS, 128, 0, stream>>>(q, Kemb, rp, fW, fb, pW, pb, p_out);
}